// Round 6
// baseline (159.637 us; speedup 1.0000x reference)
//
#include <hip/hip_runtime.h>
#include <math.h>

#define B 16
#define F 8
#define C 256
#define HW 1024
#define NROWS (B*F*C)       // 32768
#define KC 205              // ceil(0.8*256)

typedef float f4 __attribute__((ext_vector_type(4)));

// ---------------------------------------------------------------------------
// K1: per-(b,f,c) row stats over the 1024-element h*w plane.
// 2 rows per wave; all 8 dwordx4 loads in flight before reducing; shfl chains
// for both rows interleaved. 4096 blocks x 256 threads.
// ---------------------------------------------------------------------------
__global__ __launch_bounds__(256) void k_rowstat(const float* __restrict__ x,
                                                 float* __restrict__ sums,
                                                 float* __restrict__ maxs) {
    const int wave = threadIdx.x >> 6;
    const int lane = threadIdx.x & 63;
    const int row0 = blockIdx.x * 8 + wave * 2;
    const float* p0 = x + (size_t)row0 * HW + lane * 4;
    const float* p1 = p0 + HW;

    float4 a0 = *reinterpret_cast<const float4*>(p0);
    float4 a1 = *reinterpret_cast<const float4*>(p0 + 256);
    float4 a2 = *reinterpret_cast<const float4*>(p0 + 512);
    float4 a3 = *reinterpret_cast<const float4*>(p0 + 768);
    float4 b0 = *reinterpret_cast<const float4*>(p1);
    float4 b1 = *reinterpret_cast<const float4*>(p1 + 256);
    float4 b2 = *reinterpret_cast<const float4*>(p1 + 512);
    float4 b3 = *reinterpret_cast<const float4*>(p1 + 768);

    float s0 = (((a0.x + a0.y) + (a0.z + a0.w)) + ((a1.x + a1.y) + (a1.z + a1.w)))
             + (((a2.x + a2.y) + (a2.z + a2.w)) + ((a3.x + a3.y) + (a3.z + a3.w)));
    float m0 = fmaxf(fmaxf(fmaxf(fmaxf(a0.x, a0.y), fmaxf(a0.z, a0.w)),
                           fmaxf(fmaxf(a1.x, a1.y), fmaxf(a1.z, a1.w))),
                     fmaxf(fmaxf(fmaxf(a2.x, a2.y), fmaxf(a2.z, a2.w)),
                           fmaxf(fmaxf(a3.x, a3.y), fmaxf(a3.z, a3.w))));
    float s1 = (((b0.x + b0.y) + (b0.z + b0.w)) + ((b1.x + b1.y) + (b1.z + b1.w)))
             + (((b2.x + b2.y) + (b2.z + b2.w)) + ((b3.x + b3.y) + (b3.z + b3.w)));
    float m1 = fmaxf(fmaxf(fmaxf(fmaxf(b0.x, b0.y), fmaxf(b0.z, b0.w)),
                           fmaxf(fmaxf(b1.x, b1.y), fmaxf(b1.z, b1.w))),
                     fmaxf(fmaxf(fmaxf(b2.x, b2.y), fmaxf(b2.z, b2.w)),
                           fmaxf(fmaxf(b3.x, b3.y), fmaxf(b3.z, b3.w))));

#pragma unroll
    for (int off = 32; off > 0; off >>= 1) {
        s0 += __shfl_down(s0, off);
        m0 = fmaxf(m0, __shfl_down(m0, off));
        s1 += __shfl_down(s1, off);
        m1 = fmaxf(m1, __shfl_down(m1, off));
    }
    if (lane == 0) {
        sums[row0] = s0; maxs[row0] = m0;
        sums[row0 + 1] = s1; maxs[row0 + 1] = m1;
    }
}

// ---------------------------------------------------------------------------
// K2: fused attention + scale. 2048 blocks = (b, chunk) x 256 threads.
// Prologue (redundant per block, all 2048 blocks co-resident so ~one-shot):
//   tpool over c -> 8x8 time MLP -> ta[f]
//     (WTA time: k=ceil(0.9*8)=8 -> thr = min -> mask_t==1 -> sal_t = ta)
//   chan pool: c_avg = sum_f ta*sum/8192 ; c_max = max_f ta*max  (ta>0)
//   256x256 MLP x2 -> ca ; WTA: keep iff #{j: ca_j > ca_i} < 205
//   sc[c] = ca*mask  (mask^2 == mask since out = x*mask*coef, coef has mask)
// Scale: block's 16 rows (one f, 16 consecutive c): out = x * ta[f]*sc[c].
// Rows with sc==0 (~20%): store zeros WITHOUT reading x. NT stores so the
// 128 MiB output doesn't evict L3-resident x.
// ---------------------------------------------------------------------------
__global__ __launch_bounds__(256) void k_att_scale(const float* __restrict__ x,
                                                   const float* __restrict__ sums,
                                                   const float* __restrict__ maxs,
                                                   const float* __restrict__ tw1,
                                                   const float* __restrict__ tw2,
                                                   const float* __restrict__ w1,
                                                   const float* __restrict__ w2,
                                                   float* __restrict__ out) {
    __shared__ float tavg[F], tmx[F], th[F], ta_s[F];
    __shared__ float vavg[C], vmax[C], hsum[C], ca[C], sc_s[C];
    const int b     = blockIdx.x >> 7;
    const int chunk = blockIdx.x & 127;
    const int t     = threadIdx.x;
    const int wave  = t >> 6;
    const int lane  = t & 63;

    // tpool: wave w reduces f = w and f = w+4
    for (int f = wave; f < F; f += 4) {
        const float* sp = sums + (b * F + f) * C;
        const float* mp = maxs + (b * F + f) * C;
        float s = (sp[lane] + sp[lane + 64]) + (sp[lane + 128] + sp[lane + 192]);
        float m = fmaxf(fmaxf(mp[lane], mp[lane + 64]),
                        fmaxf(mp[lane + 128], mp[lane + 192]));
#pragma unroll
        for (int off = 32; off > 0; off >>= 1) {
            s += __shfl_down(s, off);
            m = fmaxf(m, __shfl_down(m, off));
        }
        if (lane == 0) { tavg[f] = s * (1.f / (float)(C * HW)); tmx[f] = m; }
    }
    __syncthreads();

    // time MLP (8x8), threads 0..7
    if (t < F) {
        float ha = 0.f, hm = 0.f;
        for (int n = 0; n < F; ++n) {
            float w = tw1[t * F + n];
            ha += w * tavg[n];
            hm += w * tmx[n];
        }
        th[t] = fmaxf(ha, 0.f) + fmaxf(hm, 0.f);
    }
    __syncthreads();
    if (t < F) {
        float o = 0.f;
        for (int h = 0; h < F; ++h) o += tw2[t * F + h] * th[h];
        ta_s[t] = 1.f / (1.f + expf(-o));
    }
    __syncthreads();

    // channel pooling of ta-scaled x via row stats (t = c)
    {
        float s = 0.f, m = -INFINITY;
        for (int f = 0; f < F; ++f) {
            float w = ta_s[f];
            s += w * sums[(b * F + f) * C + t];
            m = fmaxf(m, w * maxs[(b * F + f) * C + t]);
        }
        vavg[t] = s * (1.f / (float)(F * HW));
        vmax[t] = m;
    }
    __syncthreads();

    // channel MLP layer 1 (t = hidden)
    {
        float ha = 0.f, hm = 0.f;
        const float* w1r = w1 + t * C;
        for (int n = 0; n < C; ++n) {
            float w = w1r[n];
            ha += w * vavg[n];
            hm += w * vmax[n];
        }
        hsum[t] = fmaxf(ha, 0.f) + fmaxf(hm, 0.f);
    }
    __syncthreads();

    // layer 2 + sigmoid (t = out channel)
    float cav;
    {
        float o = 0.f;
        const float* w2r = w2 + t * C;
        for (int h = 0; h < C; ++h) o += w2r[h] * hsum[h];
        cav = 1.f / (1.f + expf(-o));
        ca[t] = cav;
    }
    __syncthreads();

    // WTA: keep iff fewer than KC strictly-greater entries
    {
        int rank = 0;
        for (int j = 0; j < C; ++j) rank += (ca[j] > cav);
        sc_s[t] = (rank < KC) ? cav : 0.f;
    }
    __syncthreads();

    // ---- scale this block's 16 rows (f = chunk>>4, c = (chunk&15)*16 + it) ----
    const float taf = ta_s[chunk >> 4];
    const int   c0  = (chunk & 15) * 16;
    const int base4 = (b * 2048 + chunk * 16) * 256;   // f4 index of row 0
    const f4* x4 = reinterpret_cast<const f4*>(x);
    f4* o4 = reinterpret_cast<f4*>(out);

    for (int it = 0; it < 16; ++it) {
        const float scv = sc_s[c0 + it];
        const int gi = base4 + it * 256 + t;
        if (scv == 0.f) {
            f4 z = {0.f, 0.f, 0.f, 0.f};
            __builtin_nontemporal_store(z, o4 + gi);
        } else {
            f4 v = x4[gi];
            v *= (taf * scv);
            __builtin_nontemporal_store(v, o4 + gi);
        }
    }
}

extern "C" void kernel_launch(void* const* d_in, const int* in_sizes, int n_in,
                              void* d_out, int out_size, void* d_ws, size_t ws_size,
                              hipStream_t stream) {
    const float* x     = (const float*)d_in[0];
    const float* ta_w1 = (const float*)d_in[1];
    const float* ta_w2 = (const float*)d_in[2];
    const float* ca_w1 = (const float*)d_in[3];
    const float* ca_w2 = (const float*)d_in[4];
    float* out = (float*)d_out;

    float* ws   = (float*)d_ws;
    float* sums = ws;                    // [32768]
    float* maxs = ws + NROWS;            // [32768]

    k_rowstat<<<NROWS / 8, 256, 0, stream>>>(x, sums, maxs);
    k_att_scale<<<B * 128, 256, 0, stream>>>(x, sums, maxs,
                                             ta_w1, ta_w2, ca_w1, ca_w2, out);
}

// Round 7
// 81.972 us; speedup vs baseline: 1.9474x; 1.9474x over previous
//
#include <hip/hip_runtime.h>
#include <math.h>

#define B 16
#define F 8
#define C 256
#define HW 1024
#define NROWS (B*F*C)       // 32768
#define KC 205              // ceil(0.8*256)

typedef float f4 __attribute__((ext_vector_type(4)));

// ---------------------------------------------------------------------------
// K1: per-(b,f,c) row stats over the 1024-element h*w plane.
// 2 rows per wave; all 8 dwordx4 loads in flight before reducing.
// 4096 blocks x 256 threads.  (measured ~12-14 us incl. gap, near L3 floor)
// ---------------------------------------------------------------------------
__global__ __launch_bounds__(256) void k_rowstat(const float* __restrict__ x,
                                                 float* __restrict__ sums,
                                                 float* __restrict__ maxs) {
    const int wave = threadIdx.x >> 6;
    const int lane = threadIdx.x & 63;
    const int row0 = blockIdx.x * 8 + wave * 2;
    const float* p0 = x + (size_t)row0 * HW + lane * 4;
    const float* p1 = p0 + HW;

    float4 a0 = *reinterpret_cast<const float4*>(p0);
    float4 a1 = *reinterpret_cast<const float4*>(p0 + 256);
    float4 a2 = *reinterpret_cast<const float4*>(p0 + 512);
    float4 a3 = *reinterpret_cast<const float4*>(p0 + 768);
    float4 b0 = *reinterpret_cast<const float4*>(p1);
    float4 b1 = *reinterpret_cast<const float4*>(p1 + 256);
    float4 b2 = *reinterpret_cast<const float4*>(p1 + 512);
    float4 b3 = *reinterpret_cast<const float4*>(p1 + 768);

    float s0 = (((a0.x + a0.y) + (a0.z + a0.w)) + ((a1.x + a1.y) + (a1.z + a1.w)))
             + (((a2.x + a2.y) + (a2.z + a2.w)) + ((a3.x + a3.y) + (a3.z + a3.w)));
    float m0 = fmaxf(fmaxf(fmaxf(fmaxf(a0.x, a0.y), fmaxf(a0.z, a0.w)),
                           fmaxf(fmaxf(a1.x, a1.y), fmaxf(a1.z, a1.w))),
                     fmaxf(fmaxf(fmaxf(a2.x, a2.y), fmaxf(a2.z, a2.w)),
                           fmaxf(fmaxf(a3.x, a3.y), fmaxf(a3.z, a3.w))));
    float s1 = (((b0.x + b0.y) + (b0.z + b0.w)) + ((b1.x + b1.y) + (b1.z + b1.w)))
             + (((b2.x + b2.y) + (b2.z + b2.w)) + ((b3.x + b3.y) + (b3.z + b3.w)));
    float m1 = fmaxf(fmaxf(fmaxf(fmaxf(b0.x, b0.y), fmaxf(b0.z, b0.w)),
                           fmaxf(fmaxf(b1.x, b1.y), fmaxf(b1.z, b1.w))),
                     fmaxf(fmaxf(fmaxf(b2.x, b2.y), fmaxf(b2.z, b2.w)),
                           fmaxf(fmaxf(b3.x, b3.y), fmaxf(b3.z, b3.w))));

#pragma unroll
    for (int off = 32; off > 0; off >>= 1) {
        s0 += __shfl_down(s0, off);
        m0 = fmaxf(m0, __shfl_down(m0, off));
        s1 += __shfl_down(s1, off);
        m1 = fmaxf(m1, __shfl_down(m1, off));
    }
    if (lane == 0) {
        sums[row0] = s0; maxs[row0] = m0;
        sums[row0 + 1] = s1; maxs[row0 + 1] = m1;
    }
}

// ---------------------------------------------------------------------------
// K2: full attention chain, one block per batch. 16 blocks x 256 threads.
//   tpool -> 8x8 time MLP -> ta[f]   (WTA time: k=8 -> mask_t==1, sal_t=ta)
//   chan pool: c_avg = sum_f ta*sum/8192 ; c_max = max_f ta*max  (ta>0)
//   256x256 MLP x2 (float4 weight rows) -> ca ; WTA rank-count
//   srow[b,f,c] = ta[f] * ca * mask        (mask^2 == mask)
// ---------------------------------------------------------------------------
__global__ __launch_bounds__(256) void k_att(const float* __restrict__ sums,
                                             const float* __restrict__ maxs,
                                             const float* __restrict__ tw1,
                                             const float* __restrict__ tw2,
                                             const float* __restrict__ w1,
                                             const float* __restrict__ w2,
                                             float* __restrict__ srow) {
    __shared__ float tavg[F], tmx[F], th[F], ta_s[F];
    __shared__ float vavg[C], vmax[C], hsum[C], ca[C];
    const int b    = blockIdx.x;
    const int t    = threadIdx.x;
    const int wave = t >> 6;
    const int lane = t & 63;

    // tpool: wave w reduces f = w and f = w+4
    for (int f = wave; f < F; f += 4) {
        const float* sp = sums + (b * F + f) * C;
        const float* mp = maxs + (b * F + f) * C;
        float s = (sp[lane] + sp[lane + 64]) + (sp[lane + 128] + sp[lane + 192]);
        float m = fmaxf(fmaxf(mp[lane], mp[lane + 64]),
                        fmaxf(mp[lane + 128], mp[lane + 192]));
#pragma unroll
        for (int off = 32; off > 0; off >>= 1) {
            s += __shfl_down(s, off);
            m = fmaxf(m, __shfl_down(m, off));
        }
        if (lane == 0) { tavg[f] = s * (1.f / (float)(C * HW)); tmx[f] = m; }
    }
    __syncthreads();

    // time MLP (8x8), threads 0..7
    if (t < F) {
        float ha = 0.f, hm = 0.f;
        for (int n = 0; n < F; ++n) {
            float w = tw1[t * F + n];
            ha += w * tavg[n];
            hm += w * tmx[n];
        }
        th[t] = fmaxf(ha, 0.f) + fmaxf(hm, 0.f);
    }
    __syncthreads();
    if (t < F) {
        float o = 0.f;
        for (int h = 0; h < F; ++h) o += tw2[t * F + h] * th[h];
        ta_s[t] = 1.f / (1.f + expf(-o));
    }
    __syncthreads();

    // channel pooling of ta-scaled x via row stats (t = c)
    {
        float s = 0.f, m = -INFINITY;
        for (int f = 0; f < F; ++f) {
            float w = ta_s[f];
            s += w * sums[(b * F + f) * C + t];
            m = fmaxf(m, w * maxs[(b * F + f) * C + t]);
        }
        vavg[t] = s * (1.f / (float)(F * HW));
        vmax[t] = m;
    }
    __syncthreads();

    // channel MLP layer 1 (t = hidden), float4 weight row
    {
        float ha = 0.f, hm = 0.f;
        const float4* w1r = reinterpret_cast<const float4*>(w1 + t * C);
        for (int n = 0; n < C / 4; ++n) {
            float4 w = w1r[n];
            ha += w.x * vavg[n*4] + w.y * vavg[n*4+1] + w.z * vavg[n*4+2] + w.w * vavg[n*4+3];
            hm += w.x * vmax[n*4] + w.y * vmax[n*4+1] + w.z * vmax[n*4+2] + w.w * vmax[n*4+3];
        }
        hsum[t] = fmaxf(ha, 0.f) + fmaxf(hm, 0.f);
    }
    __syncthreads();

    // layer 2 + sigmoid (t = out channel), float4 weight row
    float cav;
    {
        float o = 0.f;
        const float4* w2r = reinterpret_cast<const float4*>(w2 + t * C);
        for (int h = 0; h < C / 4; ++h) {
            float4 w = w2r[h];
            o += w.x * hsum[h*4] + w.y * hsum[h*4+1] + w.z * hsum[h*4+2] + w.w * hsum[h*4+3];
        }
        cav = 1.f / (1.f + expf(-o));
        ca[t] = cav;
    }
    __syncthreads();

    // WTA + combined per-row scale
    int rank = 0;
    for (int j = 0; j < C; ++j) rank += (ca[j] > cav);
    float sc = (rank < KC) ? cav : 0.f;
    for (int f = 0; f < F; ++f)
        srow[b * (F * C) + f * C + t] = ta_s[f] * sc;
}

// ---------------------------------------------------------------------------
// K3: out = x * srow[row]. 8192 blocks x 256 threads; block owns 4 rows.
// Thread t: f4 at t, t+256, t+512, t+768 (4 coalesced 1KB/wave loads in
// flight). srow loads wave-uniform. Rows with srow==0 (~20%): store zeros
// WITHOUT reading x. NT stores keep x L3-resident.
// ---------------------------------------------------------------------------
__global__ __launch_bounds__(256) void k_scale(const float* __restrict__ x,
                                               const float* __restrict__ srow,
                                               float* __restrict__ out) {
    const int row0 = blockIdx.x * 4;
    const int t = threadIdx.x;
    const f4* x4 = reinterpret_cast<const f4*>(x) + (size_t)row0 * 256;
    f4* o4 = reinterpret_cast<f4*>(out) + (size_t)row0 * 256;

    const float s0 = srow[row0], s1 = srow[row0 + 1];
    const float s2 = srow[row0 + 2], s3 = srow[row0 + 3];

    const f4 z = {0.f, 0.f, 0.f, 0.f};
    f4 v0 = z, v1 = z, v2 = z, v3 = z;
    if (s0 != 0.f) v0 = x4[t];
    if (s1 != 0.f) v1 = x4[t + 256];
    if (s2 != 0.f) v2 = x4[t + 512];
    if (s3 != 0.f) v3 = x4[t + 768];

    v0 *= s0; v1 *= s1; v2 *= s2; v3 *= s3;
    __builtin_nontemporal_store(v0, o4 + t);
    __builtin_nontemporal_store(v1, o4 + t + 256);
    __builtin_nontemporal_store(v2, o4 + t + 512);
    __builtin_nontemporal_store(v3, o4 + t + 768);
}

extern "C" void kernel_launch(void* const* d_in, const int* in_sizes, int n_in,
                              void* d_out, int out_size, void* d_ws, size_t ws_size,
                              hipStream_t stream) {
    const float* x     = (const float*)d_in[0];
    const float* ta_w1 = (const float*)d_in[1];
    const float* ta_w2 = (const float*)d_in[2];
    const float* ca_w1 = (const float*)d_in[3];
    const float* ca_w2 = (const float*)d_in[4];
    float* out = (float*)d_out;

    float* ws   = (float*)d_ws;
    float* sums = ws;                    // [32768]
    float* maxs = ws + NROWS;            // [32768]
    float* srow = ws + 2 * NROWS;        // [32768]

    k_rowstat<<<NROWS / 8, 256, 0, stream>>>(x, sums, maxs);
    k_att<<<B, 256, 0, stream>>>(sums, maxs, ta_w1, ta_w2, ca_w1, ca_w2, srow);
    k_scale<<<NROWS / 4, 256, 0, stream>>>(x, srow, out);
}